// Round 1
// baseline (253.917 us; speedup 1.0000x reference)
//
#include <hip/hip_runtime.h>

#define IN_DIM 128
#define NCOL   256   // UV row: [U(128) | V(128)]

// ---------------- GEMM: UV = z @ Weff^T ----------------
// Weff[j][k] = (j < 128) ? W1[j*256 + k] : W1[(j-128)*256 + 128 + k]
// M = n_nodes, K = 128, N = 256.
#define BM 128
#define BN 128
#define BK 32
#define PITCH (BM + 4)   // 132 floats: keeps float4 alignment, breaks pow2 bank stride

__global__ __launch_bounds__(256) void gemm_uv(
    const float* __restrict__ z, const float* __restrict__ W1,
    float* __restrict__ UV, int M)
{
    __shared__ float As[BK][PITCH];   // transposed: As[k][m]
    __shared__ float Bs[BK][PITCH];   // transposed: Bs[k][j]

    const int t  = threadIdx.x;
    const int tx = t & 15;    // N direction (8 cols each)
    const int ty = t >> 4;    // M direction (8 rows each)
    const int m0 = blockIdx.x * BM;
    const int j0 = blockIdx.y * BN;

    float acc[8][8];
#pragma unroll
    for (int i = 0; i < 8; ++i)
#pragma unroll
        for (int j = 0; j < 8; ++j) acc[i][j] = 0.f;

    for (int k0 = 0; k0 < IN_DIM; k0 += BK) {
        // ---- stage A tile (128 rows x 32 k) : 1024 float4, 4 per thread ----
#pragma unroll
        for (int s = 0; s < 4; ++s) {
            int lin = t + s * 256;        // float4 linear index
            int row = lin >> 3;           // 8 float4 per 32-float row
            int c4  = lin & 7;
            int gm  = m0 + row;
            float4 val = make_float4(0.f, 0.f, 0.f, 0.f);
            if (gm < M) val = *(const float4*)(z + (long long)gm * IN_DIM + k0 + c4 * 4);
            As[c4 * 4 + 0][row] = val.x;
            As[c4 * 4 + 1][row] = val.y;
            As[c4 * 4 + 2][row] = val.z;
            As[c4 * 4 + 3][row] = val.w;
        }
        // ---- stage B tile (128 j-rows x 32 k) ----
#pragma unroll
        for (int s = 0; s < 4; ++s) {
            int lin = t + s * 256;
            int row = lin >> 3;
            int c4  = lin & 7;
            int j   = j0 + row;
            const float* src = (j < 128) ? (W1 + j * 256 + k0 + c4 * 4)
                                         : (W1 + (j - 128) * 256 + 128 + k0 + c4 * 4);
            float4 val = *(const float4*)src;
            Bs[c4 * 4 + 0][row] = val.x;
            Bs[c4 * 4 + 1][row] = val.y;
            Bs[c4 * 4 + 2][row] = val.z;
            Bs[c4 * 4 + 3][row] = val.w;
        }
        __syncthreads();

#pragma unroll
        for (int k = 0; k < BK; ++k) {
            float4 a0 = *(const float4*)&As[k][ty * 8];
            float4 a1 = *(const float4*)&As[k][ty * 8 + 4];
            float4 b0 = *(const float4*)&Bs[k][tx * 8];
            float4 b1 = *(const float4*)&Bs[k][tx * 8 + 4];
            float am[8] = {a0.x, a0.y, a0.z, a0.w, a1.x, a1.y, a1.z, a1.w};
            float bn[8] = {b0.x, b0.y, b0.z, b0.w, b1.x, b1.y, b1.z, b1.w};
#pragma unroll
            for (int i = 0; i < 8; ++i)
#pragma unroll
                for (int j = 0; j < 8; ++j)
                    acc[i][j] = fmaf(am[i], bn[j], acc[i][j]);
        }
        __syncthreads();
    }

    // ---- store 8x8 per thread ----
#pragma unroll
    for (int i = 0; i < 8; ++i) {
        int gm = m0 + ty * 8 + i;
        if (gm >= M) continue;
        float4 v0 = make_float4(acc[i][0], acc[i][1], acc[i][2], acc[i][3]);
        float4 v1 = make_float4(acc[i][4], acc[i][5], acc[i][6], acc[i][7]);
        float* dst = UV + (long long)gm * NCOL + j0 + tx * 8;
        *(float4*)(dst)     = v0;
        *(float4*)(dst + 4) = v1;
    }
}

// ---------------- per-edge MLP ----------------
// one edge per 16-lane group; lane handles 8 hidden channels.
__global__ __launch_bounds__(256) void edge_mlp(
    const float* __restrict__ UV, const int* __restrict__ ei,
    const float* __restrict__ b1, const float* __restrict__ W2,
    const float* __restrict__ b2, float* __restrict__ out, int E)
{
    const int gt   = blockIdx.x * blockDim.x + threadIdx.x;
    const int lane = threadIdx.x & 15;
    const int e    = gt >> 4;
    const int j0   = lane * 8;

    // per-lane constants (same for every edge this lane touches)
    float bb[8], ww[8];
    {
        float4 bb0 = *(const float4*)(b1 + j0);
        float4 bb1 = *(const float4*)(b1 + j0 + 4);
        float4 ww0 = *(const float4*)(W2 + j0);
        float4 ww1 = *(const float4*)(W2 + j0 + 4);
        bb[0]=bb0.x; bb[1]=bb0.y; bb[2]=bb0.z; bb[3]=bb0.w;
        bb[4]=bb1.x; bb[5]=bb1.y; bb[6]=bb1.z; bb[7]=bb1.w;
        ww[0]=ww0.x; ww[1]=ww0.y; ww[2]=ww0.z; ww[3]=ww0.w;
        ww[4]=ww1.x; ww[5]=ww1.y; ww[6]=ww1.z; ww[7]=ww1.w;
    }

    if (e >= E) return;

    const int srcn = ei[e];
    const int dstn = ei[E + e];

    const float4* up = (const float4*)(UV + (long long)srcn * NCOL + j0);
    const float4* vp = (const float4*)(UV + (long long)dstn * NCOL + 128 + j0);
    float4 u0 = up[0], u1 = up[1];
    float4 v0 = vp[0], v1 = vp[1];

    float uu[8] = {u0.x, u0.y, u0.z, u0.w, u1.x, u1.y, u1.z, u1.w};
    float vv[8] = {v0.x, v0.y, v0.z, v0.w, v1.x, v1.y, v1.z, v1.w};

    float s = 0.f;
#pragma unroll
    for (int i = 0; i < 8; ++i) {
        float h = uu[i] + vv[i] + bb[i];
        h = fmaxf(h, 0.f);
        s = fmaf(h, ww[i], s);
    }

    // reduce across the 16-lane group (xor stays inside the group)
    s += __shfl_xor(s, 1);
    s += __shfl_xor(s, 2);
    s += __shfl_xor(s, 4);
    s += __shfl_xor(s, 8);

    if (lane == 0) out[e] = s + b2[0];
}

extern "C" void kernel_launch(void* const* d_in, const int* in_sizes, int n_in,
                              void* d_out, int out_size, void* d_ws, size_t ws_size,
                              hipStream_t stream)
{
    const float* z  = (const float*)d_in[0];
    const int*   ei = (const int*)d_in[1];   // int32 per harness integer rule
    const float* W1 = (const float*)d_in[2];
    const float* b1 = (const float*)d_in[3];
    const float* W2 = (const float*)d_in[4];
    const float* b2 = (const float*)d_in[5];
    float* out = (float*)d_out;

    const int M = in_sizes[0] / IN_DIM;   // 100000 nodes
    const int E = in_sizes[1] / 2;        // 600000 edges

    float* UV = (float*)d_ws;             // [M][256] = 102.4 MB

    dim3 ggrid((M + BM - 1) / BM, NCOL / BN);   // (782, 2)
    gemm_uv<<<ggrid, 256, 0, stream>>>(z, W1, UV, M);

    int eblocks = (E + 15) / 16;                // 16 edges per 256-thread block
    edge_mlp<<<eblocks, 256, 0, stream>>>(UV, ei, b1, W2, b2, out, E);
}

// Round 2
// 190.459 us; speedup vs baseline: 1.3332x; 1.3332x over previous
//
#include <hip/hip_runtime.h>

#define IN_DIM 128
#define NCOL   256   // UV row: [U(128) | V(128)], bf16

typedef __bf16 bfx8 __attribute__((ext_vector_type(8)));
typedef float  f32x4 __attribute__((ext_vector_type(4)));

// ---------------- GEMM: UV = bf16( z @ Weff^T ) + [b1 | 0] ----------------
// Weff[n][k] = (n < 128) ? W1[n][k] : W1[n-128][128+k]   (W1 is [128][256] row-major)
// M = n_nodes, K = 128, N = 256. MFMA 16x16x32 bf16, B entirely in registers.
// Block = 256 threads = 4 waves; wave w owns n-slice [w*64, w*64+64).
// Each block iteration covers a 32-row m-chunk; grid-stride over 3125 chunks.
__global__ __launch_bounds__(256) void gemm_mfma(
    const float* __restrict__ z, const float* __restrict__ W1,
    const float* __restrict__ b1, __bf16* __restrict__ UV, int M)
{
    const int tid  = threadIdx.x;
    const int wave = tid >> 6;
    const int lane = tid & 63;
    const int l15  = lane & 15;
    const int q    = lane >> 4;      // quad index 0..3
    const int n0   = wave * 64;

    // --- B fragments: lane holds Weff[n][k], n = n0+nt*16+l15, k = kk*32+q*8+j ---
    bfx8  bfrag[4][4];
    float bias[4];
#pragma unroll
    for (int nt = 0; nt < 4; ++nt) {
        const int n = n0 + nt * 16 + l15;
        bias[nt] = (n < 128) ? b1[n] : 0.f;
#pragma unroll
        for (int kk = 0; kk < 4; ++kk) {
            const int k = kk * 32 + q * 8;
            const float* p = (n < 128) ? (W1 + n * 256 + k)
                                       : (W1 + (n - 128) * 256 + 128 + k);
            float4 f0 = *(const float4*)p;
            float4 f1 = *(const float4*)(p + 4);
            bfx8 b;
            b[0] = (__bf16)f0.x; b[1] = (__bf16)f0.y; b[2] = (__bf16)f0.z; b[3] = (__bf16)f0.w;
            b[4] = (__bf16)f1.x; b[5] = (__bf16)f1.y; b[6] = (__bf16)f1.z; b[7] = (__bf16)f1.w;
            bfrag[nt][kk] = b;
        }
    }

    for (int m0 = blockIdx.x * 32; m0 < M; m0 += gridDim.x * 32) {
        f32x4 acc[2][4];
#pragma unroll
        for (int mt = 0; mt < 2; ++mt)
#pragma unroll
            for (int nt = 0; nt < 4; ++nt)
                acc[mt][nt] = (f32x4){0.f, 0.f, 0.f, 0.f};

#pragma unroll
        for (int kk = 0; kk < 4; ++kk) {
            bfx8 afrag[2];
#pragma unroll
            for (int mt = 0; mt < 2; ++mt) {
                int row = m0 + mt * 16 + l15;
                if (row >= M) row = M - 1;          // clamp (M is a multiple of 32 anyway)
                const float* p = z + (size_t)row * IN_DIM + kk * 32 + q * 8;
                float4 f0 = *(const float4*)p;
                float4 f1 = *(const float4*)(p + 4);
                bfx8 a;
                a[0] = (__bf16)f0.x; a[1] = (__bf16)f0.y; a[2] = (__bf16)f0.z; a[3] = (__bf16)f0.w;
                a[4] = (__bf16)f1.x; a[5] = (__bf16)f1.y; a[6] = (__bf16)f1.z; a[7] = (__bf16)f1.w;
                afrag[mt] = a;
            }
#pragma unroll
            for (int mt = 0; mt < 2; ++mt)
#pragma unroll
                for (int nt = 0; nt < 4; ++nt)
                    acc[mt][nt] = __builtin_amdgcn_mfma_f32_16x16x32_bf16(
                        afrag[mt], bfrag[nt][kk], acc[mt][nt], 0, 0, 0);
        }

        // --- epilogue: fp32 bias add, round to bf16, store ---
        // D mapping: col = l15 (n), row = q*4 + r
#pragma unroll
        for (int mt = 0; mt < 2; ++mt) {
#pragma unroll
            for (int nt = 0; nt < 4; ++nt) {
                const int col = n0 + nt * 16 + l15;
#pragma unroll
                for (int r = 0; r < 4; ++r) {
                    const int row = m0 + mt * 16 + q * 4 + r;
                    if (row < M)
                        UV[(size_t)row * NCOL + col] = (__bf16)(acc[mt][nt][r] + bias[nt]);
                }
            }
        }
    }
}

// ---------------- per-edge MLP ----------------
// one edge per 16-lane group; lane handles 8 hidden channels (16 B bf16 loads).
// b1 is already folded into U; h = relu(u+v), out = h . w2 + b2.
__global__ __launch_bounds__(256) void edge_mlp(
    const __bf16* __restrict__ UV, const int* __restrict__ ei,
    const float* __restrict__ W2, const float* __restrict__ b2,
    float* __restrict__ out, int E)
{
    const int gt   = blockIdx.x * blockDim.x + threadIdx.x;
    const int lane = threadIdx.x & 15;
    const int e    = gt >> 4;
    const int j0   = lane * 8;

    float ww[8];
    {
        float4 w0 = *(const float4*)(W2 + j0);
        float4 w1 = *(const float4*)(W2 + j0 + 4);
        ww[0] = w0.x; ww[1] = w0.y; ww[2] = w0.z; ww[3] = w0.w;
        ww[4] = w1.x; ww[5] = w1.y; ww[6] = w1.z; ww[7] = w1.w;
    }

    if (e >= E) return;

    const int srcn = ei[e];
    const int dstn = ei[E + e];

    bfx8 u = *(const bfx8*)(UV + (size_t)srcn * NCOL + j0);
    bfx8 v = *(const bfx8*)(UV + (size_t)dstn * NCOL + 128 + j0);

    float s = 0.f;
#pragma unroll
    for (int i = 0; i < 8; ++i) {
        float h = (float)u[i] + (float)v[i];
        h = fmaxf(h, 0.f);
        s = fmaf(h, ww[i], s);
    }

    s += __shfl_xor(s, 1);
    s += __shfl_xor(s, 2);
    s += __shfl_xor(s, 4);
    s += __shfl_xor(s, 8);

    if (lane == 0) out[e] = s + b2[0];
}

extern "C" void kernel_launch(void* const* d_in, const int* in_sizes, int n_in,
                              void* d_out, int out_size, void* d_ws, size_t ws_size,
                              hipStream_t stream)
{
    const float* z  = (const float*)d_in[0];
    const int*   ei = (const int*)d_in[1];
    const float* W1 = (const float*)d_in[2];
    const float* b1 = (const float*)d_in[3];
    const float* W2 = (const float*)d_in[4];
    const float* b2 = (const float*)d_in[5];
    float* out = (float*)d_out;

    const int M = in_sizes[0] / IN_DIM;   // 100000 nodes
    const int E = in_sizes[1] / 2;        // 600000 edges

    __bf16* UV = (__bf16*)d_ws;           // [M][256] bf16 = 51.2 MB

    gemm_mfma<<<625, 256, 0, stream>>>(z, W1, b1, UV, M);

    int eblocks = (E * 16 + 255) / 256;   // 16 edges per 256-thread block
    edge_mlp<<<eblocks, 256, 0, stream>>>(UV, ei, W2, b2, out, E);
}

// Round 3
// 175.552 us; speedup vs baseline: 1.4464x; 1.0849x over previous
//
#include <hip/hip_runtime.h>

#define IN_DIM 128
#define NCOL   256   // UV row: [U(128) | V(128)], bf16
#define TPITCH (NCOL + 8)   // LDS tile pitch in bf16 (528 B, 16B-aligned, breaks pow2)

typedef __bf16 bfx8 __attribute__((ext_vector_type(8)));
typedef __bf16 bfx4 __attribute__((ext_vector_type(4)));
typedef float  f32x4 __attribute__((ext_vector_type(4)));

// ---------------- pre-pass: Weff[n][k] = bf16 of the fused layer-1 weight ----------------
// Weff[n][k] = (n<128) ? W1[n][k] : W1[n-128][128+k];  [256][128] bf16, 64 KB.
__global__ __launch_bounds__(256) void prep_w(
    const float* __restrict__ W1, __bf16* __restrict__ Weff)
{
    const int n = threadIdx.x;    // one row per thread, 256 threads
    const float* src = (n < 128) ? (W1 + n * 256) : (W1 + (n - 128) * 256 + 128);
    __bf16* dst = Weff + n * IN_DIM;
#pragma unroll
    for (int k = 0; k < IN_DIM; k += 4) {
        float4 f = *(const float4*)(src + k);
        bfx4 b;
        b[0] = (__bf16)f.x; b[1] = (__bf16)f.y; b[2] = (__bf16)f.z; b[3] = (__bf16)f.w;
        *(bfx4*)(dst + k) = b;
    }
}

// ---------------- GEMM: UV = bf16( z @ Weff^T + [b1|0] ) ----------------
// M=100000, K=128, N=256. MFMA 16x16x32 bf16, B entirely in registers.
// Block = 256 threads = 4 waves; wave w owns n-slice [w*64, w*64+64).
// Each block covers 2 chunks of 32 rows. Epilogue goes through LDS for
// coalesced dwordx4 stores.
__global__ __launch_bounds__(256) void gemm_mfma(
    const float* __restrict__ z, const __bf16* __restrict__ Weff,
    const float* __restrict__ b1, __bf16* __restrict__ UV, int M)
{
    __shared__ __bf16 tile[32][TPITCH];

    const int tid  = threadIdx.x;
    const int wave = tid >> 6;
    const int lane = tid & 63;
    const int l15  = lane & 15;
    const int q    = lane >> 4;      // quad 0..3
    const int n0   = wave * 64;

    // --- B fragments from pre-packed bf16 Weff: lane holds Weff[n][kk*32+q*8 ..+8] ---
    bfx8  bfrag[4][4];
    float bias[4];
#pragma unroll
    for (int nt = 0; nt < 4; ++nt) {
        const int n = n0 + nt * 16 + l15;
        bias[nt] = (n < 128) ? b1[n] : 0.f;
#pragma unroll
        for (int kk = 0; kk < 4; ++kk)
            bfrag[nt][kk] = *(const bfx8*)(Weff + n * IN_DIM + kk * 32 + q * 8);
    }

    const int mbeg = blockIdx.x * 64;
    const int mend = (mbeg + 64 < M) ? (mbeg + 64) : M;   // M % 32 == 0

    for (int m0 = mbeg; m0 < mend; m0 += 32) {
        // --- preload all 8 A fragments (independent loads -> ILP) ---
        bfx8 afrag[2][4];
#pragma unroll
        for (int mt = 0; mt < 2; ++mt) {
#pragma unroll
            for (int kk = 0; kk < 4; ++kk) {
                const float* p = z + (size_t)(m0 + mt * 16 + l15) * IN_DIM + kk * 32 + q * 8;
                float4 f0 = *(const float4*)p;
                float4 f1 = *(const float4*)(p + 4);
                bfx8 a;
                a[0] = (__bf16)f0.x; a[1] = (__bf16)f0.y; a[2] = (__bf16)f0.z; a[3] = (__bf16)f0.w;
                a[4] = (__bf16)f1.x; a[5] = (__bf16)f1.y; a[6] = (__bf16)f1.z; a[7] = (__bf16)f1.w;
                afrag[mt][kk] = a;
            }
        }

        f32x4 acc[2][4];
#pragma unroll
        for (int mt = 0; mt < 2; ++mt)
#pragma unroll
            for (int nt = 0; nt < 4; ++nt)
                acc[mt][nt] = (f32x4){0.f, 0.f, 0.f, 0.f};

#pragma unroll
        for (int kk = 0; kk < 4; ++kk)
#pragma unroll
            for (int mt = 0; mt < 2; ++mt)
#pragma unroll
                for (int nt = 0; nt < 4; ++nt)
                    acc[mt][nt] = __builtin_amdgcn_mfma_f32_16x16x32_bf16(
                        afrag[mt][kk], bfrag[nt][kk], acc[mt][nt], 0, 0, 0);

        // --- epilogue: bias + round to bf16 into LDS tile (col=l15, row=q*4+r) ---
#pragma unroll
        for (int mt = 0; mt < 2; ++mt)
#pragma unroll
            for (int nt = 0; nt < 4; ++nt) {
                const int col = n0 + nt * 16 + l15;
#pragma unroll
                for (int r = 0; r < 4; ++r)
                    tile[mt * 16 + q * 4 + r][col] = (__bf16)(acc[mt][nt][r] + bias[nt]);
            }
        __syncthreads();

        // --- coalesced store: 32 rows x 512 B, 16 B per thread per pass ---
#pragma unroll
        for (int s = 0; s < 4; ++s) {
            const int lin = s * 256 + tid;      // dwordx4 index in 32x256 tile
            const int row = lin >> 5;
            const int c   = lin & 31;
            bfx8 v = *(const bfx8*)&tile[row][c * 8];
            *(bfx8*)(UV + (size_t)(m0 + row) * NCOL + c * 8) = v;
        }
        __syncthreads();
    }
}

// ---------------- per-edge MLP ----------------
// 16-lane group handles 2 edges (ILP: 4 independent 16 B gathers in flight).
// lane covers 8 hidden channels; b1 already folded into U.
__global__ __launch_bounds__(256) void edge_mlp(
    const __bf16* __restrict__ UV, const int* __restrict__ ei,
    const float* __restrict__ W2, const float* __restrict__ b2,
    float* __restrict__ out, int E)
{
    const int gt   = blockIdx.x * blockDim.x + threadIdx.x;
    const int lane = threadIdx.x & 15;
    const int g    = gt >> 4;
    const int e0   = g * 2;
    const int j0   = lane * 8;

    float ww[8];
    {
        float4 w0 = *(const float4*)(W2 + j0);
        float4 w1 = *(const float4*)(W2 + j0 + 4);
        ww[0] = w0.x; ww[1] = w0.y; ww[2] = w0.z; ww[3] = w0.w;
        ww[4] = w1.x; ww[5] = w1.y; ww[6] = w1.z; ww[7] = w1.w;
    }

    if (e0 >= E) return;   // E is even

    const int2 srcp = *(const int2*)(ei + e0);       // src of e0, e0+1
    const int2 dstp = *(const int2*)(ei + E + e0);   // dst of e0, e0+1

    bfx8 u0 = *(const bfx8*)(UV + (size_t)srcp.x * NCOL + j0);
    bfx8 v0 = *(const bfx8*)(UV + (size_t)dstp.x * NCOL + 128 + j0);
    bfx8 u1 = *(const bfx8*)(UV + (size_t)srcp.y * NCOL + j0);
    bfx8 v1 = *(const bfx8*)(UV + (size_t)dstp.y * NCOL + 128 + j0);

    float s0 = 0.f, s1 = 0.f;
#pragma unroll
    for (int i = 0; i < 8; ++i) {
        float h0 = (float)u0[i] + (float)v0[i];
        float h1 = (float)u1[i] + (float)v1[i];
        s0 = fmaf(fmaxf(h0, 0.f), ww[i], s0);
        s1 = fmaf(fmaxf(h1, 0.f), ww[i], s1);
    }

#pragma unroll
    for (int d = 1; d < 16; d <<= 1) {
        s0 += __shfl_xor(s0, d);
        s1 += __shfl_xor(s1, d);
    }

    if (lane == 0) {
        float bb = b2[0];
        *(float2*)(out + e0) = make_float2(s0 + bb, s1 + bb);
    }
}

extern "C" void kernel_launch(void* const* d_in, const int* in_sizes, int n_in,
                              void* d_out, int out_size, void* d_ws, size_t ws_size,
                              hipStream_t stream)
{
    const float* z  = (const float*)d_in[0];
    const int*   ei = (const int*)d_in[1];
    const float* W1 = (const float*)d_in[2];
    const float* b1 = (const float*)d_in[3];
    const float* W2 = (const float*)d_in[4];
    const float* b2 = (const float*)d_in[5];
    float* out = (float*)d_out;

    const int M = in_sizes[0] / IN_DIM;   // 100000 nodes
    const int E = in_sizes[1] / 2;        // 600000 edges

    __bf16* UV   = (__bf16*)d_ws;                       // [M][256] bf16 = 51.2 MB
    __bf16* Weff = UV + (size_t)M * NCOL;               // [256][128] bf16 = 64 KB

    prep_w<<<1, 256, 0, stream>>>(W1, Weff);

    int gblocks = (M + 63) / 64;                        // 1563: 2 chunks of 32 rows each
    gemm_mfma<<<gblocks, 256, 0, stream>>>(z, Weff, b1, UV, M);

    int groups  = (E + 1) / 2;                          // 2 edges per 16-lane group
    int eblocks = (groups * 16 + 255) / 256;            // 18750
    edge_mlp<<<eblocks, 256, 0, stream>>>(UV, ei, W2, b2, out, E);
}